// Round 2
// baseline (1258.533 us; speedup 1.0000x reference)
//
#include <hip/hip_runtime.h>
#include <cstdint>
#include <cstddef>

constexpr int kBS = 8;
constexpr int kNC = 64;
constexpr int kC = 256;
constexpr int kD = 32;
constexpr int kK = 16;
constexpr int kKB = 8;
constexpr int kALPHA = 4;
constexpr int kB = 16;
constexpr int kHS = 64;
constexpr int kHM = 64;
constexpr int kHMOD = 32;
constexpr int kN = kNC * kC;               // 16384
constexpr int kMODIN = kK + 3 * kD + 1;    // 113
constexpr int kMODOUT = kK + kKB + 1 + kD; // 57

constexpr size_t kO1 = (size_t)kBS * kNC * kD;        // readout = 16384
constexpr size_t kO2 = kO1 + (size_t)kBS * kN * kD;   // + h_new
constexpr size_t kO3 = kO2 + (size_t)kBS * kN * kD;   // + msg

__device__ __forceinline__ float fast_sigmoid(float x) {
    return __builtin_amdgcn_rcpf(1.0f + __expf(-x));
}
__device__ __forceinline__ float fast_tanh(float x) {
    float e = __expf(2.0f * x);
    return 1.0f - 2.0f * __builtin_amdgcn_rcpf(e + 1.0f);
}

// ---------------- Kernel A: per-neuron modulation MLP --------------------
// One wave per neuron. Lane layout for compute: b = lane&7 (batch), slot = lane>>3.
// LDS rows stride 120 floats -> distinct-row bank groups {0,8,16,24} = 2-way (free).
__global__ __launch_bounds__(64) void mod_mlp_kernel(
    const float* __restrict__ heb, const float* __restrict__ h,
    const float* __restrict__ dlog, const float* __restrict__ prim,
    const float* __restrict__ nid,
    const float* __restrict__ mw1, const float* __restrict__ mb1,
    const float* __restrict__ mw2, const float* __restrict__ mb2,
    float* __restrict__ modout)
{
    const int n = blockIdx.x;
    const int lane = threadIdx.x;
    const int b8 = lane & 7;
    const int slot = lane >> 3;

    __shared__ __align__(16) float w1s[kHMOD * 120]; // W1 padded; reused as W2^T (57x36)
    __shared__ __align__(16) float flats[kBS * 120];
    __shared__ __align__(16) float hids[kBS * 36];
    __shared__ float b1s[kHMOD];
    __shared__ float b2s[64];

    // stage W1: flat float4 global loads (coalesced), scalar LDS scatter to padded rows
    const float* w1g = mw1 + (size_t)n * (kHMOD * kMODIN);
    for (int idx = lane; idx < 904; idx += 64) {   // 3616 floats = 904 float4
        float4 v = ((const float4*)w1g)[idx];
        int f = idx * 4;
        int r = f / 113, c0 = f - r * 113;
        float tmp[4] = {v.x, v.y, v.z, v.w};
        #pragma unroll
        for (int e = 0; e < 4; ++e) {
            int r2 = r, c2 = c0 + e;
            if (c2 >= 113) { r2++; c2 -= 113; }
            w1s[r2 * 120 + c2] = tmp[e];
        }
    }
    if (lane < kHMOD) b1s[lane] = mb1[(size_t)n * kHMOD + lane];

    // stage mod inputs: [heb(16), h(32), dlog(1), prim(32), nid(32)]
    for (int t = lane; t < 128; t += 64) { int bb = t >> 4, i = t & 15; flats[bb*120 + i]      = heb[((size_t)bb*kN + n)*kK + i]; }
    for (int t = lane; t < 256; t += 64) { int bb = t >> 5, i = t & 31; flats[bb*120 + 16 + i] = h[((size_t)bb*kN + n)*kD + i]; }
    if (lane < 8) flats[lane*120 + 48] = dlog[(size_t)lane*kN + n];
    for (int t = lane; t < 256; t += 64) { int bb = t >> 5, i = t & 31; flats[bb*120 + 49 + i] = prim[((size_t)bb*kN + n)*kD + i]; }
    for (int t = lane; t < 256; t += 64) { int bb = t >> 5, i = t & 31; flats[bb*120 + 81 + i] = nid[(size_t)n*kD + i]; }
    __syncthreads();

    // layer 1: lane computes hh = slot + 8*jj for its batch b8. x broadcast (free),
    // 8 distinct w-rows per instr at 2-way bank aliasing (free).
    float acc[4];
    #pragma unroll
    for (int jj = 0; jj < 4; ++jj) acc[jj] = b1s[slot + 8*jj];
    const float4* xr = (const float4*)(flats + b8 * 120);
    #pragma unroll
    for (int q = 0; q < 28; ++q) {
        float4 xv = xr[q];
        #pragma unroll
        for (int jj = 0; jj < 4; ++jj) {
            float4 wv = ((const float4*)(w1s + (slot + 8*jj) * 120))[q];
            acc[jj] += xv.x*wv.x + xv.y*wv.y + xv.z*wv.z + xv.w*wv.w;
        }
    }
    {
        float xt = flats[b8*120 + 112];
        #pragma unroll
        for (int jj = 0; jj < 4; ++jj) acc[jj] += xt * w1s[(slot + 8*jj)*120 + 112];
    }
    #pragma unroll
    for (int jj = 0; jj < 4; ++jj) hids[b8*36 + slot + 8*jj] = fast_tanh(acc[jj]);
    __syncthreads();   // layer-1 reads of w1s done; hids visible

    // stage W2 transposed into w1s: w2t[o*36 + hh]  (2052 floats <= 3840)
    const float* w2g = mw2 + (size_t)n * (kHMOD * kMODOUT); // [hh][o]
    for (int t = lane; t < kHMOD * kMODOUT; t += 64) {
        int hh = t / kMODOUT; int o = t - hh * kMODOUT;
        w1s[o*36 + hh] = w2g[t];
    }
    if (lane < kMODOUT) b2s[lane] = mb2[(size_t)n * kMODOUT + lane];
    __syncthreads();

    // layer 2: hids row cached in registers; w2t rows via float4 broadcast reads
    float hreg[32];
    {
        const float4* hr = (const float4*)(hids + b8 * 36);
        #pragma unroll
        for (int q = 0; q < 8; ++q) { float4 v = hr[q]; hreg[4*q]=v.x; hreg[4*q+1]=v.y; hreg[4*q+2]=v.z; hreg[4*q+3]=v.w; }
    }
    float* moutp = modout + ((size_t)b8 * kN + n) * kMODOUT;
    #pragma unroll
    for (int jj = 0; jj < 8; ++jj) {
        int o = slot + 8*jj;
        if (o < kMODOUT) {
            float a2 = b2s[o];
            const float4* wr = (const float4*)(w1s + o * 36);
            #pragma unroll
            for (int q = 0; q < 8; ++q) {
                float4 wv = wr[q];
                a2 += hreg[4*q]*wv.x + hreg[4*q+1]*wv.y + hreg[4*q+2]*wv.z + hreg[4*q+3]*wv.w;
            }
            moutp[o] = a2;
        }
    }
}

// ---------------- Kernel B: per-cell message passing + state/msg MLPs -----
// grid (NC, BS, 2). Block handles 128 neurons with 2 wave-uniform parts
// (part = t>>7) splitting the hidden dim; partials reduced via the slab LDS.
__global__ __launch_bounds__(256, 3) void cell_kernel(
    const float* __restrict__ cc, const float* __restrict__ hin,
    const float* __restrict__ pmsg, const float* __restrict__ prim,
    const float* __restrict__ nid,
    const float* __restrict__ sw1, const float* __restrict__ sb1,
    const float* __restrict__ sw2, const float* __restrict__ sb2,
    const float* __restrict__ mw1g, const float* __restrict__ mb1g,
    const float* __restrict__ mw2g, const float* __restrict__ mb2g,
    const int* __restrict__ conn, const int* __restrict__ bconn,
    const float* __restrict__ modout, float* __restrict__ out)
{
    const int nc = blockIdx.x, b = blockIdx.y, split = blockIdx.z;
    const int t = threadIdx.x;
    const int part = t >> 7;   // wave-uniform
    const int cl = t & 127;
    const int c = split * 128 + cl;

    __shared__ float slab[kC * 33];

    const size_t cellrow = ((size_t)b * kNC + nc) * (size_t)kC;
    const size_t nbase = cellrow + c;

    { // stage full cell's prev_messages
        const float* src = pmsg + cellrow * kD;
        for (int i = t; i < kC * kD; i += 256) slab[(i >> 5) * 33 + (i & 31)] = src[i];
    }

    float hreg[32];
    {
        const float4* s = (const float4*)(hin + nbase * kD);
        #pragma unroll
        for (int q = 0; q < 8; ++q) { float4 v = s[q]; hreg[4*q]=v.x; hreg[4*q+1]=v.y; hreg[4*q+2]=v.z; hreg[4*q+3]=v.w; }
    }
    const float* mo = modout + nbase * kMODOUT;
    int jreg[8];
    {
        const int4* cr = (const int4*)(conn + ((size_t)nc * kC + c) * kK + part * 8);
        #pragma unroll
        for (int q = 0; q < 2; ++q) { int4 v = cr[q]; jreg[4*q]=v.x; jreg[4*q+1]=v.y; jreg[4*q+2]=v.z; jreg[4*q+3]=v.w; }
    }
    float wcon[8];
    #pragma unroll
    for (int kk = 0; kk < 8; ++kk) wcon[kk] = fast_sigmoid(mo[part * 8 + kk]);
    const float decay = fast_sigmoid(mo[kK + kKB]);
    float pnew[32];
    {
        const float4* s = (const float4*)(prim + nbase * kD);
        #pragma unroll
        for (int q = 0; q < 8; ++q) {
            float4 v = s[q];
            pnew[4*q]   = v.x + mo[25 + 4*q];
            pnew[4*q+1] = v.y + mo[25 + 4*q + 1];
            pnew[4*q+2] = v.z + mo[25 + 4*q + 2];
            pnew[4*q+3] = v.w + mo[25 + 4*q + 3];
        }
    }
    __syncthreads();

    // partial received: this part's 8 conn gathers (+ border half / cc)
    float recv[32];
    #pragma unroll
    for (int d = 0; d < 32; ++d) recv[d] = 0.f;
    #pragma unroll 1
    for (int kk = 0; kk < 8; ++kk) {
        const float* row = slab + jreg[kk] * 33;
        float w = wcon[kk];
        #pragma unroll
        for (int d = 0; d < 32; ++d) recv[d] += row[d] * w;
    }
    if (c >= kALPHA && c < kALPHA + kB) {
        int j = c - kALPHA;
        const int* br = bconn + ((size_t)nc * kB + j) * kKB + part * 4;
        #pragma unroll 1
        for (int q = 0; q < 4; ++q) {
            int g = br[q];
            int nc2 = g >> 4, c2 = kALPHA + (g & 15);
            const float* src = pmsg + (((size_t)b * kNC + nc2) * kC + c2) * kD;
            float w = fast_sigmoid(mo[kK + part * 4 + q]);
            #pragma unroll
            for (int d = 0; d < 32; ++d) recv[d] += src[d] * w;
        }
    }
    if (part == 0 && c < kALPHA) {
        const float* src = cc + (size_t)b * (kNC * kD) + nc * kD;
        #pragma unroll
        for (int d = 0; d < 32; ++d) recv[d] += src[d];
    }
    __syncthreads();                 // slab gather reads done -> reuse as reduce buf
    #pragma unroll
    for (int d = 0; d < 32; ++d) slab[t * 33 + d] = recv[d];
    __syncthreads();
    #pragma unroll
    for (int d = 0; d < 32; ++d) recv[d] += slab[(t ^ 128) * 33 + d];
    __syncthreads();

    // state MLP partial over hh = part*32 .. +31
    float dh[32];
    #pragma unroll
    for (int o = 0; o < 32; ++o) dh[o] = 0.f;
    #pragma unroll 2
    for (int hx = 0; hx < 32; ++hx) {
        int hh = part * 32 + hx;                 // wave-uniform -> s_load weights
        const float* w = sw1 + hh * 97;
        float acc = sb1[hh];
        #pragma unroll
        for (int i = 0; i < 32; ++i) acc += hreg[i] * w[i];
        #pragma unroll
        for (int i = 0; i < 32; ++i) acc += recv[i] * w[32 + i];
        #pragma unroll
        for (int i = 0; i < 32; ++i) acc += pnew[i] * w[64 + i];
        acc += decay * w[96];
        float s = fast_tanh(acc);
        const float* w2 = sw2 + hh;
        #pragma unroll
        for (int o = 0; o < 32; ++o) dh[o] += s * w2[o * 64];
    }
    #pragma unroll
    for (int d = 0; d < 32; ++d) slab[t * 33 + d] = dh[d];
    __syncthreads();
    #pragma unroll
    for (int d = 0; d < 32; ++d) dh[d] += slab[(t ^ 128) * 33 + d];
    float hnew[32];
    #pragma unroll
    for (int d = 0; d < 32; ++d) hnew[d] = decay * hreg[d] + (1.f - decay) * fast_tanh(dh[d] + sb2[d]);
    {   // split the h_new store between parts
        float4* dst = (float4*)(out + kO1 + nbase * kD);
        #pragma unroll
        for (int q = 0; q < 4; ++q) {
            int qq = part * 4 + q;
            dst[qq] = make_float4(hnew[4*qq], hnew[4*qq+1], hnew[4*qq+2], hnew[4*qq+3]);
        }
    }

    // msg MLP partial
    float nidr[32];
    {
        const float4* s = (const float4*)(nid + ((size_t)nc * kC + c) * kD);
        #pragma unroll
        for (int q = 0; q < 8; ++q) { float4 v = s[q]; nidr[4*q]=v.x; nidr[4*q+1]=v.y; nidr[4*q+2]=v.z; nidr[4*q+3]=v.w; }
    }
    float mm[32];
    #pragma unroll
    for (int o = 0; o < 32; ++o) mm[o] = 0.f;
    #pragma unroll 2
    for (int hx = 0; hx < 32; ++hx) {
        int hh = part * 32 + hx;
        const float* w = mw1g + hh * 96;
        float acc = mb1g[hh];
        #pragma unroll
        for (int i = 0; i < 32; ++i) acc += hnew[i] * w[i];
        #pragma unroll
        for (int i = 0; i < 32; ++i) acc += recv[i] * w[32 + i];
        #pragma unroll
        for (int i = 0; i < 32; ++i) acc += nidr[i] * w[64 + i];
        float s = fast_tanh(acc);
        const float* w2 = mw2g + hh;
        #pragma unroll
        for (int o = 0; o < 32; ++o) mm[o] += s * w2[o * 64];
    }
    __syncthreads();                 // partner's dh reads done -> safe to overwrite
    #pragma unroll
    for (int d = 0; d < 32; ++d) slab[t * 33 + d] = mm[d];
    __syncthreads();
    #pragma unroll
    for (int d = 0; d < 32; ++d) mm[d] += slab[(t ^ 128) * 33 + d];
    float msgr[32];
    #pragma unroll
    for (int d = 0; d < 32; ++d) msgr[d] = fast_tanh(mm[d] + mb2g[d]);
    __syncthreads();                 // partner's mm reads done
    if (part == 0) {
        #pragma unroll
        for (int d = 0; d < 32; ++d) slab[cl * 33 + d] = msgr[d];
    }
    __syncthreads();
    {   // coalesced msg dump for this block's 128 neurons
        float* dst = out + kO2 + cellrow * kD + (size_t)split * 128 * kD;
        for (int i = t; i < 128 * kD; i += 256) dst[i] = slab[(i >> 5) * 33 + (i & 31)];
    }
    if (split == 1 && t < kD) {      // readout: mean of msg rows 252..255 (local 124..127)
        float s = 0.25f * (slab[124*33 + t] + slab[125*33 + t] + slab[126*33 + t] + slab[127*33 + t]);
        out[(size_t)b * (kNC * kD) + nc * kD + t] = s;
    }
}

// ---------------- Kernel C: hebbian trace update --------------------------
// Needs all 256 msgs of a cell -> separate dispatch after cell_kernel.
__global__ __launch_bounds__(256) void hebb_kernel(
    const float* __restrict__ hebin, const int* __restrict__ conn,
    float* __restrict__ out)
{
    const int nc = blockIdx.x, b = blockIdx.y, c = threadIdx.x;
    __shared__ float slab[kC * 33];
    const size_t cellrow = ((size_t)b * kNC + nc) * (size_t)kC;
    const float* msgg = out + kO2 + cellrow * kD;
    for (int i = c; i < kC * kD; i += 256) slab[(i >> 5) * 33 + (i & 31)] = msgg[i];
    int jreg[16];
    {
        const int4* cr = (const int4*)(conn + ((size_t)nc * kC + c) * kK);
        #pragma unroll
        for (int q = 0; q < 4; ++q) { int4 v = cr[q]; jreg[4*q]=v.x; jreg[4*q+1]=v.y; jreg[4*q+2]=v.z; jreg[4*q+3]=v.w; }
    }
    __syncthreads();
    float msgr[32];
    #pragma unroll
    for (int d = 0; d < 32; ++d) msgr[d] = slab[c * 33 + d];
    const size_t nbase = cellrow + c;
    const float* hb = hebin + nbase * kK;
    float res[16];
    #pragma unroll 1
    for (int k = 0; k < 16; ++k) {
        const float* row = slab + jreg[k] * 33;
        float dot = 0.f;
        #pragma unroll
        for (int d = 0; d < 32; ++d) dot += msgr[d] * row[d];
        res[k] = 0.9f * hb[k] + 0.1f * (dot * (1.0f / 32.0f));
    }
    {
        float4* dst = (float4*)(out + kO3 + nbase * kK);
        #pragma unroll
        for (int q = 0; q < 4; ++q) dst[q] = make_float4(res[4*q], res[4*q+1], res[4*q+2], res[4*q+3]);
    }
}

extern "C" void kernel_launch(void* const* d_in, const int* in_sizes, int n_in,
                              void* d_out, int out_size, void* d_ws, size_t ws_size,
                              hipStream_t stream)
{
    const float* cc    = (const float*)d_in[0];
    const float* h     = (const float*)d_in[1];
    const float* pmsg  = (const float*)d_in[2];
    const float* dlog  = (const float*)d_in[3];
    const float* prim  = (const float*)d_in[4];
    const float* heb   = (const float*)d_in[5];
    const float* sw1   = (const float*)d_in[6];
    const float* sb1   = (const float*)d_in[7];
    const float* sw2   = (const float*)d_in[8];
    const float* sb2   = (const float*)d_in[9];
    const float* mw1   = (const float*)d_in[10];
    const float* mb1   = (const float*)d_in[11];
    const float* mw2   = (const float*)d_in[12];
    const float* mb2   = (const float*)d_in[13];
    const float* modw1 = (const float*)d_in[14];
    const float* modb1 = (const float*)d_in[15];
    const float* modw2 = (const float*)d_in[16];
    const float* modb2 = (const float*)d_in[17];
    const float* nid   = (const float*)d_in[18];
    const int*   conn  = (const int*)d_in[19];
    const int*   bconn = (const int*)d_in[20];
    float* out = (float*)d_out;
    float* modout = (float*)d_ws;   // (BS, N, 57) = 29.9 MB scratch

    mod_mlp_kernel<<<kN, 64, 0, stream>>>(heb, h, dlog, prim, nid,
                                          modw1, modb1, modw2, modb2, modout);
    cell_kernel<<<dim3(kNC, kBS, 2), 256, 0, stream>>>(cc, h, pmsg, prim, nid,
                                                       sw1, sb1, sw2, sb2,
                                                       mw1, mb1, mw2, mb2,
                                                       conn, bconn, modout, out);
    hebb_kernel<<<dim3(kNC, kBS), 256, 0, stream>>>(heb, conn, out);
}